// Round 1
// baseline (646.364 us; speedup 1.0000x reference)
//
#include <hip/hip_runtime.h>
#include <hip/hip_bf16.h>

// Problem constants (fixed by the reference setup_inputs)
constexpr int N_NODES = 50000;
constexpr int M_EDGES = 20000;
constexpr int E_INC   = 200000;
constexpr int H_HEADS = 8;
constexpr int C_CTX   = 64;
constexpr int NE_OUT  = 200000;
constexpr int R_REL   = 3 * N_NODES; // 150000

constexpr int STRIPS  = 256;         // 256x4 = 1024 blocks = 4 blocks/CU
constexpr int SROWS   = 586;         // ceil(150000/256)
constexpr int SCHUNKS = 10;          // ceil(586/64)

typedef short bf8v __attribute__((ext_vector_type(8)));   // 8 bf16 (4 VGPRs)
typedef float f4v  __attribute__((ext_vector_type(4)));   // 4 fp32 acc
#define MFMA16(a, b, c) __builtin_amdgcn_mfma_f32_16x16x32_bf16(a, b, c, 0, 0, 0)

// fp32 -> bf16 (RNE) scalar; compiler emits v_cvt equivalents
__device__ __forceinline__ unsigned short bfs(float f) {
    union { __hip_bfloat16 b; unsigned short s; } u;
    u.b = __float2bfloat16(f);
    return u.s;
}
// packed pair: low short = lo, high short = hi (v_cvt_pk_bf16_f32)
__device__ __forceinline__ unsigned bfp(float lo, float hi) {
    union { __hip_bfloat162 b; unsigned u; } v;
    v.b = __float22bfloat162_rn(make_float2(lo, hi));
    return v.u;
}

// ---------------------------------------------------------------- zero fill
__global__ __launch_bounds__(256) void zero_kernel(float4* p, int n4) {
    int i = blockIdx.x * 256 + threadIdx.x;
    if (i < n4) p[i] = make_float4(0.f, 0.f, 0.f, 0.f);
}

// ------------------------------------------- theta -> bf16 transposed [n][k]
__global__ __launch_bounds__(256) void wconv_kernel(
    const float* __restrict__ t0, const float* __restrict__ t1,
    const float* __restrict__ t2, unsigned short* __restrict__ out)
{
    int idx = blockIdx.x * 256 + threadIdx.x;   // 0..49151
    int m = idx >> 14, p = idx & 16383;
    int n = p >> 7, k = p & 127;
    const float* src = (m == 0) ? t0 : (m == 1) ? t1 : t2;
    out[idx] = bfs(src[k * 128 + n]);
}

// ---- fused q-projection + qk/cb precompute. grid 64 (one block per c).
// qk[hc][j] = 0.25 * sum_d q[c,h16+d]*wk[j,h16+d];  cb[hc] = 0.25*q.bk
__global__ __launch_bounds__(256) void qkf_kernel(
    const float* __restrict__ ctx, const float* __restrict__ wq,
    const float* __restrict__ bq, const float* __restrict__ wk,
    const float* __restrict__ bk, unsigned short* __restrict__ qkb,
    float* __restrict__ cb)
{
    __shared__ float qrow[128];
    const int c = blockIdx.x, t = threadIdx.x;
    if (t < 128) {
        float s = bq[t];
        for (int k = 0; k < 128; ++k) s += ctx[c * 128 + k] * wq[(size_t)k * 128 + t];
        qrow[t] = s;
    }
    __syncthreads();
#pragma unroll
    for (int i = 0; i < 4; ++i) {
        int idx = t + i * 256;          // 0..1023
        int h = idx >> 7, j = idx & 127;
        const float* wr = wk + (size_t)j * 128 + h * 16;
        const float* qr = qrow + h * 16;
        float s = 0.f;
#pragma unroll
        for (int d = 0; d < 16; ++d) s += qr[d] * wr[d];
        qkb[(size_t)(h * 64 + c) * 128 + j] = bfs(0.25f * s);
    }
    if (t < 8) {
        float s = 0.f;
#pragma unroll
        for (int d = 0; d < 16; ++d) s += qrow[t * 16 + d] * bk[t * 16 + d];
        cb[t * 64 + c] = 0.25f * s;
    }
}

// ------------------- xt(bf16) = x(fp32) @ theta  via MFMA, grid (391, 3)
__global__ __launch_bounds__(256) void xg_kernel(
    const float* __restrict__ x0, const float* __restrict__ x1,
    const float* __restrict__ x2, const unsigned short* __restrict__ thT,
    unsigned short* __restrict__ y, int R)
{
    int m = blockIdx.y;
    const float* X = (m == 0) ? x0 : (m == 1) ? x1 : x2;
    const unsigned short* W = thT + m * 16384;
    unsigned short* Y = y + (size_t)m * R * 128;
    const int w = threadIdx.x >> 6, lane = threadIdx.x & 63;
    const int ln15 = lane & 15, l16 = lane >> 4;
    const int r0 = blockIdx.x * 128 + w * 32;

    f4v acc[2][8];
#pragma unroll
    for (int i = 0; i < 2; ++i)
#pragma unroll
        for (int j = 0; j < 8; ++j) acc[i][j] = (f4v)0.f;

    for (int ks = 0; ks < 4; ++ks) {
        bf8v a[2];
#pragma unroll
        for (int mt = 0; mt < 2; ++mt) {
            int row = r0 + mt * 16 + ln15;
            row = (row < R) ? row : (R - 1);
            const float* xp = X + (size_t)row * 128 + ks * 32 + l16 * 8;
            float4 f0 = *(const float4*)xp;
            float4 f1 = *(const float4*)(xp + 4);
            union { bf8v v; unsigned w[4]; } u;
            u.w[0] = bfp(f0.x, f0.y);
            u.w[1] = bfp(f0.z, f0.w);
            u.w[2] = bfp(f1.x, f1.y);
            u.w[3] = bfp(f1.z, f1.w);
            a[mt] = u.v;
        }
#pragma unroll
        for (int nt = 0; nt < 8; ++nt) {
            bf8v b = *(const bf8v*)(W + (nt * 16 + ln15) * 128 + ks * 32 + l16 * 8);
            acc[0][nt] = MFMA16(a[0], b, acc[0][nt]);
            acc[1][nt] = MFMA16(a[1], b, acc[1][nt]);
        }
    }
#pragma unroll
    for (int mt = 0; mt < 2; ++mt)
#pragma unroll
        for (int reg = 0; reg < 4; ++reg) {
            int row = r0 + mt * 16 + l16 * 4 + reg;
            if (row < R) {
#pragma unroll
                for (int nt = 0; nt < 8; ++nt)
                    Y[(size_t)row * 128 + nt * 16 + ln15] = bfs(acc[mt][nt][reg]);
            }
        }
}

// --------------------------------------------------- CSR build: count (x6)
__global__ __launch_bounds__(256) void count6_kernel(
    const int* e0, const int* e1, const int* e2,
    const int* n0, const int* n1, const int* n2, int* cntbase)
{
    int b = blockIdx.y;
    const int* arr = (b == 0) ? e0 : (b == 1) ? e1 : (b == 2) ? e2
                   : (b == 3) ? n0 : (b == 4) ? n1 : n2;
    int base = (b < 3) ? b * M_EDGES : 3 * M_EDGES + (b - 3) * N_NODES;
    int i = blockIdx.x * 256 + threadIdx.x;
    if (i < E_INC) atomicAdd(cntbase + base + arr[i], 1);
}

// ------------------------------------- CSR build: 6-way scan, 1024 threads
__global__ __launch_bounds__(1024) void scan6_kernel(
    const int* __restrict__ cnts, int* __restrict__ offs)
{
    const int lens[6] = {M_EDGES, M_EDGES, M_EDGES, N_NODES, N_NODES, N_NODES};
    int b = blockIdx.x;
    int cbase = 0, obase = 0;
    for (int i = 0; i < b; ++i) { cbase += lens[i]; obase += lens[i] + 1; }
    const int* cnt = cnts + cbase;
    int* off = offs + obase;
    const int len = lens[b];
    const int t = threadIdx.x, lane = t & 63, w = t >> 6;   // 16 waves
    __shared__ int wsum[2][16];
    int carry = 0, buf = 0;
    for (int base = 0; base < len; base += 4096, buf ^= 1) {
        int i0 = base + t * 4;
        int v0 = (i0 + 0 < len) ? cnt[i0 + 0] : 0;
        int v1 = (i0 + 1 < len) ? cnt[i0 + 1] : 0;
        int v2 = (i0 + 2 < len) ? cnt[i0 + 2] : 0;
        int v3 = (i0 + 3 < len) ? cnt[i0 + 3] : 0;
        int s = v0 + v1 + v2 + v3;
        int incl = s;
#pragma unroll
        for (int d = 1; d < 64; d <<= 1) {
            int x = __shfl_up(incl, d, 64);
            if (lane >= d) incl += x;
        }
        if (lane == 63) wsum[buf][w] = incl;
        __syncthreads();
        int prefix = carry;
        for (int ww = 0; ww < w; ++ww) prefix += wsum[buf][ww];
        int excl = prefix + incl - s;
        if (i0 + 0 < len) off[i0 + 0] = excl;
        if (i0 + 1 < len) off[i0 + 1] = excl + v0;
        if (i0 + 2 < len) off[i0 + 2] = excl + v0 + v1;
        if (i0 + 3 < len) off[i0 + 3] = excl + v0 + v1 + v2;
#pragma unroll
        for (int ww = 0; ww < 16; ++ww) carry += wsum[buf][ww];
    }
    if (t == 0) off[len] = carry;
}

// --------------------------------------------------- CSR build: fill (x6)
__global__ __launch_bounds__(256) void fill6_kernel(
    const int* e0, const int* e1, const int* e2,
    const int* n0, const int* n1, const int* n2,
    int* cntbase, const int* offbase, int* listbase)
{
    int b = blockIdx.y;
    const int* idx   = (b == 0) ? e0 : (b == 1) ? e1 : (b == 2) ? e2
                     : (b == 3) ? n0 : (b == 4) ? n1 : n2;
    const int* other = (b == 0) ? n0 : (b == 1) ? n1 : (b == 2) ? n2
                     : (b == 3) ? e0 : (b == 4) ? e1 : e2;
    int cb = (b < 3) ? b * M_EDGES : 3 * M_EDGES + (b - 3) * N_NODES;
    int ob = (b < 3) ? b * (M_EDGES + 1) : 3 * (M_EDGES + 1) + (b - 3) * (N_NODES + 1);
    int* cnt = cntbase + cb;
    const int* off = offbase + ob;
    int* list = listbase + (size_t)b * E_INC;
    int i = blockIdx.x * 256 + threadIdx.x;
    if (i >= E_INC) return;
    int e = idx[i];
    int pos = atomicSub(&cnt[e], 1) - 1;
    list[off[e] + pos] = other[i];
}

// ------------------- ebuf[e,:] = mean of xt rows (bf16), grid (2500, 3)
__global__ __launch_bounds__(256) void gedge_kernel(
    const unsigned short* __restrict__ xt,
    const int* __restrict__ listbase, const int* __restrict__ offbase,
    unsigned short* __restrict__ eb)
{
    int mm = blockIdx.y;
    const unsigned short* X = xt + (size_t)mm * N_NODES * 128;
    const int* list = listbase + (size_t)mm * E_INC;
    const int* off = offbase + mm * (M_EDGES + 1);
    unsigned short* E = eb + (size_t)mm * M_EDGES * 128;
    int t = blockIdx.x * 256 + threadIdx.x;
    int e = t >> 5, lane = t & 31;
    if (e >= M_EDGES) return;
    int s = off[e], en = off[e + 1];
    float a0 = 0, a1 = 0, a2 = 0, a3 = 0;
    for (int j = s; j < en; ++j) {
        int n = list[j];
        uint2 v = *(const uint2*)(X + (size_t)n * 128 + lane * 4);
        a0 += __uint_as_float(v.x << 16);
        a1 += __uint_as_float(v.x & 0xFFFF0000u);
        a2 += __uint_as_float(v.y << 16);
        a3 += __uint_as_float(v.y & 0xFFFF0000u);
    }
    float bi = (en > s) ? 1.f / (float)(en - s) : 0.f;
    uint2 o;
    o.x = bfp(a0 * bi, a1 * bi);
    o.y = bfp(a2 * bi, a3 * bi);
    *(uint2*)(E + (size_t)e * 128 + lane * 4) = o;
}

// ------------ rel[n,:] = mean of ebuf rows + bias (bf16), grid (6250, 3)
__global__ __launch_bounds__(256) void gnode_kernel(
    const unsigned short* __restrict__ eb,
    const int* __restrict__ listbase, const int* __restrict__ offbase,
    const float* __restrict__ b0, const float* __restrict__ b1,
    const float* __restrict__ b2, unsigned short* __restrict__ rel)
{
    int mm = blockIdx.y;
    const unsigned short* E = eb + (size_t)mm * M_EDGES * 128;
    const int* list = listbase + (size_t)(3 + mm) * E_INC;
    const int* off = offbase + 3 * (M_EDGES + 1) + mm * (N_NODES + 1);
    const float* bias = (mm == 0) ? b0 : (mm == 1) ? b1 : b2;
    unsigned short* R = rel + (size_t)mm * N_NODES * 128;
    int t = blockIdx.x * 256 + threadIdx.x;
    int n = t >> 5, lane = t & 31;
    if (n >= N_NODES) return;
    int s = off[n], en = off[n + 1];
    float a0 = 0, a1 = 0, a2 = 0, a3 = 0;
    for (int j = s; j < en; ++j) {
        int e = list[j];
        uint2 v = *(const uint2*)(E + (size_t)e * 128 + lane * 4);
        a0 += __uint_as_float(v.x << 16);
        a1 += __uint_as_float(v.x & 0xFFFF0000u);
        a2 += __uint_as_float(v.y << 16);
        a3 += __uint_as_float(v.y & 0xFFFF0000u);
    }
    float di = (en > s) ? 1.f / (float)(en - s) : 0.f;
    uint2 o;
    o.x = bfp(a0 * di + bias[lane * 4 + 0], a1 * di + bias[lane * 4 + 1]);
    o.y = bfp(a2 * di + bias[lane * 4 + 2], a3 * di + bias[lane * 4 + 3]);
    *(uint2*)(R + (size_t)n * 128 + lane * 4) = o;
}

// ------------------------------- fused attention: grid (256 strips, 4 pairs)
// GEMM1: S = rel @ qk^T (+cb), p = exp(S); GEMM2: PR += P^T @ rel; l = colsums
__global__ __launch_bounds__(256) void attn_kernel(
    const unsigned short* __restrict__ rel, const unsigned short* __restrict__ qkb,
    const float* __restrict__ cb, float* __restrict__ PRpart, float* __restrict__ lpart)
{
    __shared__ __align__(16) unsigned short relT[128 * 72];
    __shared__ __align__(16) unsigned short Pl[128 * 72];

    const int strip = blockIdx.x, pair = blockIdx.y;
    const int t = threadIdx.x, w = t >> 6, lane = t & 63;
    const int ln15 = lane & 15, l16 = lane >> 4;

    bf8v bq[2][4];
#pragma unroll
    for (int nt = 0; nt < 2; ++nt)
#pragma unroll
        for (int ks = 0; ks < 4; ++ks)
            bq[nt][ks] = *(const bf8v*)(qkb +
                (size_t)(pair * 128 + w * 32 + nt * 16 + ln15) * 128 + ks * 32 + l16 * 8);
    float cbr[2];
#pragma unroll
    for (int nt = 0; nt < 2; ++nt)
        cbr[nt] = cb[pair * 128 + w * 32 + nt * 16 + ln15];

    f4v pr[2][8];
#pragma unroll
    for (int i = 0; i < 2; ++i)
#pragma unroll
        for (int j = 0; j < 8; ++j) pr[i][j] = (f4v)0.f;
    float lacc[2] = {0.f, 0.f};

    const int r0s = strip * SROWS;
    const int rend = (r0s + SROWS < R_REL) ? (r0s + SROWS) : R_REL;

    for (int cidx = 0; cidx < SCHUNKS; ++cidx) {
        const int base = r0s + cidx * 64;
        if (base >= rend) break;
        const int nvalid = rend - base;
        __syncthreads();
        // ---- stage relT[j][r] (transposed, padded stride 72) ----
        uint* RT = (uint*)relT;
#pragma unroll
        for (int a = 0; a < 2; ++a) {
            int idx = t + a * 256;
            int rp = idx & 31, jg = idx >> 5;   // r-pair, j-group
            const unsigned short* p0 = rel + (size_t)(base + rp * 2) * 128 + jg * 8;
            uint4 A = *(const uint4*)p0;
            uint4 B = *(const uint4*)(p0 + 128);
            unsigned aw[4] = {A.x, A.y, A.z, A.w};
            unsigned bw[4] = {B.x, B.y, B.z, B.w};
#pragma unroll
            for (int jj = 0; jj < 4; ++jj) {
                int j0 = jg * 8 + jj * 2;
                RT[(j0    ) * 36 + rp] = (aw[jj] & 0xFFFFu) | (bw[jj] << 16);
                RT[(j0 + 1) * 36 + rp] = (aw[jj] >> 16) | (bw[jj] & 0xFFFF0000u);
            }
        }
        // ---- GEMM1: S[r, hc] ----
        f4v sc[4][2];
#pragma unroll
        for (int i = 0; i < 4; ++i) { sc[i][0] = (f4v)0.f; sc[i][1] = (f4v)0.f; }
        for (int ks = 0; ks < 4; ++ks) {
            bf8v a[4];
#pragma unroll
            for (int mt = 0; mt < 4; ++mt)
                a[mt] = *(const bf8v*)(rel + (size_t)(base + mt * 16 + ln15) * 128 + ks * 32 + l16 * 8);
#pragma unroll
            for (int mt = 0; mt < 4; ++mt) {
                sc[mt][0] = MFMA16(a[mt], bq[0][ks], sc[mt][0]);
                sc[mt][1] = MFMA16(a[mt], bq[1][ks], sc[mt][1]);
            }
        }
        // ---- exp + mask + Pl (packed bf16x2 writes) + l ----
        bool full = (nvalid >= 64);
        unsigned* PW = (unsigned*)Pl;
#pragma unroll
        for (int nt = 0; nt < 2; ++nt) {
            float ls = 0.f;
#pragma unroll
            for (int mt = 0; mt < 4; ++mt) {
                float pv[4];
#pragma unroll
                for (int reg = 0; reg < 4; ++reg) {
                    int rl = mt * 16 + l16 * 4 + reg;
                    float p = __expf(sc[mt][nt][reg] + cbr[nt]);
                    if (!full && rl >= nvalid) p = 0.f;
                    ls += p;
                    pv[reg] = p;
                }
                int base2 = ((w * 32 + nt * 16 + ln15) * 72 + mt * 16 + l16 * 4) >> 1;
                PW[base2] = bfp(pv[0], pv[1]);
                PW[base2 + 1] = bfp(pv[2], pv[3]);
            }
            ls += __shfl_xor(ls, 16, 64);
            ls += __shfl_xor(ls, 32, 64);
            lacc[nt] += ls;
        }
        __syncthreads();
        // ---- GEMM2: PR[hc, j] += P^T @ rel ----
        for (int ks = 0; ks < 2; ++ks) {
            bf8v ap[2];
#pragma unroll
            for (int mt = 0; mt < 2; ++mt)
                ap[mt] = *(const bf8v*)(Pl + (w * 32 + mt * 16 + ln15) * 72 + ks * 32 + l16 * 8);
#pragma unroll
            for (int nt = 0; nt < 8; ++nt) {
                bf8v b = *(const bf8v*)(relT + (nt * 16 + ln15) * 72 + ks * 32 + l16 * 8);
                pr[0][nt] = MFMA16(ap[0], b, pr[0][nt]);
                pr[1][nt] = MFMA16(ap[1], b, pr[1][nt]);
            }
        }
    }
    // ---- write partials ----
    float* PB = PRpart + (size_t)(pair * STRIPS + strip) * 128 * 128;
#pragma unroll
    for (int mt = 0; mt < 2; ++mt)
#pragma unroll
        for (int reg = 0; reg < 4; ++reg) {
            int hcl = w * 32 + mt * 16 + l16 * 4 + reg;
#pragma unroll
            for (int nt = 0; nt < 8; ++nt)
                PB[hcl * 128 + nt * 16 + ln15] = pr[mt][nt][reg];
        }
    if (lane < 16) {
        float* LB = lpart + (size_t)(pair * STRIPS + strip) * 128;
        LB[w * 32 + ln15] = lacc[0];
        LB[w * 32 + 16 + ln15] = lacc[1];
    }
}

// ---------------- reduce: PRsum -> o_norm -> osum (atomic), grid 512
__global__ __launch_bounds__(256) void reduce_kernel(
    const float* __restrict__ PRpart, const float* __restrict__ lpart,
    const float* __restrict__ wv, const float* __restrict__ bv,
    float* __restrict__ osum)
{
    int hc = blockIdx.x;
    int pair = hc >> 7, hcl = hc & 127, h = hc >> 6;
    __shared__ float PS[128];
    __shared__ float LL[129];
    int t = threadIdx.x;
    if (t < 128) {
        float s = 0.f;
        const float* p = PRpart + ((size_t)(pair * STRIPS) * 128 + hcl) * 128 + t;
        for (int st = 0; st < STRIPS; ++st) s += p[(size_t)st * 128 * 128];
        PS[t] = s;
    } else {
        int idx = t - 128;   // 0..127, each covers 2 strips
        LL[idx] = lpart[(size_t)(pair * STRIPS + idx) * 128 + hcl]
                + lpart[(size_t)(pair * STRIPS + idx + 128) * 128 + hcl];
    }
    __syncthreads();
    if (t == 0) {
        float l = 0.f;
        for (int st = 0; st < 128; ++st) l += LL[st];
        LL[128] = l;
    }
    __syncthreads();
    if (t < 16) {
        float o = 0.f;
        for (int j = 0; j < 128; ++j) o += PS[j] * wv[(size_t)j * 128 + h * 16 + t];
        float on = o / LL[128] + bv[h * 16 + t];
        atomicAdd(&osum[h * 16 + t], on);
    }
}

// --- u[d] = (sum_c ctx[c,d] + (osum@wo)[d]/64 + bo[d]) / 65
__global__ __launch_bounds__(128) void user_kernel(
    const float* __restrict__ ctx, const float* __restrict__ osum,
    const float* __restrict__ wo, const float* __restrict__ bo,
    float* __restrict__ u)
{
    __shared__ float os[128];
    int d = threadIdx.x;
    os[d] = osum[d];
    __syncthreads();
    float cs = 0.f;
    for (int cc = 0; cc < 64; ++cc) cs += ctx[cc * 128 + d];
    float ow = 0.f;
    for (int j = 0; j < 128; ++j) ow += os[j] * wo[j * 128 + d];
    u[d] = (cs + ow * (1.f / 64.f) + bo[d]) * (1.f / 65.f);
}

// --------------------------------- out[j] = u @ w_rec[:,j] + b_rec[j]
__global__ __launch_bounds__(256) void rec_kernel(
    const float* __restrict__ u, const float* __restrict__ wrec,
    const float* __restrict__ brec, float* __restrict__ out)
{
    __shared__ float ul[128];
    if (threadIdx.x < 128) ul[threadIdx.x] = u[threadIdx.x];
    __syncthreads();
    int j = blockIdx.x * 256 + threadIdx.x;
    if (j >= NE_OUT) return;
    float a0 = brec[j], a1 = 0.f, a2 = 0.f, a3 = 0.f;
#pragma unroll 4
    for (int d = 0; d < 128; d += 4) {
        a0 += ul[d + 0] * wrec[(size_t)(d + 0) * NE_OUT + j];
        a1 += ul[d + 1] * wrec[(size_t)(d + 1) * NE_OUT + j];
        a2 += ul[d + 2] * wrec[(size_t)(d + 2) * NE_OUT + j];
        a3 += ul[d + 3] * wrec[(size_t)(d + 3) * NE_OUT + j];
    }
    out[j] = (a0 + a1) + (a2 + a3);
}

extern "C" void kernel_launch(void* const* d_in, const int* in_sizes, int n_in,
                              void* d_out, int out_size, void* d_ws, size_t ws_size,
                              hipStream_t stream)
{
    const float* ctx  = (const float*)d_in[9];
    const float* wq = (const float*)d_in[10];
    const float* bq = (const float*)d_in[11];
    const float* wk = (const float*)d_in[12];
    const float* bk = (const float*)d_in[13];
    const float* wv = (const float*)d_in[14];
    const float* bv = (const float*)d_in[15];
    const float* wo = (const float*)d_in[16];
    const float* bo = (const float*)d_in[17];
    const float* wrec = (const float*)d_in[18];
    const float* brec = (const float*)d_in[19];
    const int* node0 = (const int*)d_in[20];
    const int* edge0 = (const int*)d_in[21];
    const int* node1 = (const int*)d_in[22];
    const int* edge1 = (const int*)d_in[23];
    const int* node2 = (const int*)d_in[24];
    const int* edge2 = (const int*)d_in[25];
    float* out = (float*)d_out;

    char* ws = (char*)d_ws;
    size_t off = 0;
    auto alloc = [&](size_t nbytes) {
        void* p = ws + off;
        off += (nbytes + 255) & ~(size_t)255;
        return p;
    };
    unsigned short* rel  = (unsigned short*)alloc((size_t)R_REL * 128 * 2);
    unsigned short* xt   = (unsigned short*)alloc((size_t)3 * N_NODES * 128 * 2);
    unsigned short* eb   = (unsigned short*)alloc((size_t)3 * M_EDGES * 128 * 2);
    float* PRpart = (float*)alloc((size_t)4 * STRIPS * 128 * 128 * 4);   // 67 MB
    float* lpart  = (float*)alloc((size_t)4 * STRIPS * 128 * 4);
    unsigned short* qkb = (unsigned short*)alloc(512 * 128 * 2);
    float* cbv    = (float*)alloc(512 * 4);
    unsigned short* thT = (unsigned short*)alloc(3 * 16384 * 2);
    int* cntbase  = (int*)alloc((size_t)(3 * M_EDGES + 3 * N_NODES + 128) * 4); // + osum
    float* osum   = (float*)(cntbase + 3 * M_EDGES + 3 * N_NODES);
    int* offbase  = (int*)alloc((size_t)(3 * (M_EDGES + 1) + 3 * (N_NODES + 1)) * 4);
    int* listbase = (int*)alloc((size_t)6 * E_INC * 4);
    float* u      = (float*)alloc(128 * 4);
    (void)ws_size; (void)in_sizes; (void)n_in; (void)out_size;

    // 1. zero cnt + osum (contiguous)
    {
        int nwords = 3 * M_EDGES + 3 * N_NODES + 128;   // 210128, /4 = 52532
        zero_kernel<<<(nwords / 4 + 255) / 256, 256, 0, stream>>>((float4*)cntbase, nwords / 4);
    }
    // 2-4. CSR build
    const int gE = (E_INC + 255) / 256;
    count6_kernel<<<dim3(gE, 6), 256, 0, stream>>>(edge0, edge1, edge2, node0, node1, node2, cntbase);
    scan6_kernel<<<6, 1024, 0, stream>>>(cntbase, offbase);
    fill6_kernel<<<dim3(gE, 6), 256, 0, stream>>>(edge0, edge1, edge2, node0, node1, node2,
                                                  cntbase, offbase, listbase);
    // 5. weight conversion (theta^T bf16)
    wconv_kernel<<<192, 256, 0, stream>>>((const float*)d_in[1], (const float*)d_in[4],
                                          (const float*)d_in[7], thT);
    // 6. fused q projection + qk/cb precompute
    qkf_kernel<<<64, 256, 0, stream>>>(ctx, wq, bq, wk, bk, qkb, cbv);
    // 7. xt = x @ theta (bf16 MFMA), all modalities
    xg_kernel<<<dim3((N_NODES + 127) / 128, 3), 256, 0, stream>>>(
        (const float*)d_in[0], (const float*)d_in[3], (const float*)d_in[6], thT, xt, N_NODES);
    // 8-9. gathers
    gedge_kernel<<<dim3(M_EDGES * 32 / 256, 3), 256, 0, stream>>>(xt, listbase, offbase, eb);
    gnode_kernel<<<dim3(N_NODES * 32 / 256, 3), 256, 0, stream>>>(
        eb, listbase, offbase, (const float*)d_in[2], (const float*)d_in[5],
        (const float*)d_in[8], rel);
    // 10-11. fused attention + reduce
    attn_kernel<<<dim3(STRIPS, 4), 256, 0, stream>>>(rel, qkb, cbv, PRpart, lpart);
    reduce_kernel<<<512, 256, 0, stream>>>(PRpart, lpart, wv, bv, osum);
    // 12-13. user repr + final scores
    user_kernel<<<1, 128, 0, stream>>>(ctx, osum, wo, bo, u);
    rec_kernel<<<(NE_OUT + 255) / 256, 256, 0, stream>>>(u, wrec, brec, out);
}

// Round 2
// 598.250 us; speedup vs baseline: 1.0804x; 1.0804x over previous
//
#include <hip/hip_runtime.h>
#include <hip/hip_bf16.h>

// Problem constants (fixed by the reference setup_inputs)
constexpr int N_NODES = 50000;
constexpr int M_EDGES = 20000;
constexpr int E_INC   = 200000;
constexpr int H_HEADS = 8;
constexpr int C_CTX   = 64;
constexpr int NE_OUT  = 200000;
constexpr int R_REL   = 3 * N_NODES; // 150000

constexpr int STRIPS  = 256;         // 256x4 = 1024 blocks
constexpr int SROWS   = 586;         // ceil(150000/256)

typedef short bf8v __attribute__((ext_vector_type(8)));   // 8 bf16 (4 VGPRs)
typedef float f4v  __attribute__((ext_vector_type(4)));   // 4 fp32 acc
#define MFMA16(a, b, c) __builtin_amdgcn_mfma_f32_16x16x32_bf16(a, b, c, 0, 0, 0)

// fp32 -> bf16 (RNE) scalar; compiler emits v_cvt equivalents
__device__ __forceinline__ unsigned short bfs(float f) {
    union { __hip_bfloat16 b; unsigned short s; } u;
    u.b = __float2bfloat16(f);
    return u.s;
}
// packed pair: low short = lo, high short = hi (v_cvt_pk_bf16_f32)
__device__ __forceinline__ unsigned bfp(float lo, float hi) {
    union { __hip_bfloat162 b; unsigned u; } v;
    v.b = __float22bfloat162_rn(make_float2(lo, hi));
    return v.u;
}

// async global->LDS 16B per lane. LDS dest = wave-uniform base + lane*16 (HW).
// Avoid addrspacecast issues: AS1 ptr == flat global addr; AS3 ptr == low 32 bits
// of the flat LDS addr (gfx9+ aperture layout).
__device__ __forceinline__ void gload16(const void* g, const void* l) {
    __builtin_amdgcn_global_load_lds(
        (const __attribute__((address_space(1))) void*)(unsigned long long)(size_t)g,
        (__attribute__((address_space(3))) void*)(unsigned)(size_t)l,
        16, 0, 0);
}

// ---------------------------------------------------------------- zero fill
__global__ __launch_bounds__(256) void zero_kernel(float4* p, int n4) {
    int i = blockIdx.x * 256 + threadIdx.x;
    if (i < n4) p[i] = make_float4(0.f, 0.f, 0.f, 0.f);
}

// ------------------------------------------- theta -> bf16 transposed [n][k]
__global__ __launch_bounds__(256) void wconv_kernel(
    const float* __restrict__ t0, const float* __restrict__ t1,
    const float* __restrict__ t2, unsigned short* __restrict__ out)
{
    int idx = blockIdx.x * 256 + threadIdx.x;   // 0..49151
    int m = idx >> 14, p = idx & 16383;
    int n = p >> 7, k = p & 127;
    const float* src = (m == 0) ? t0 : (m == 1) ? t1 : t2;
    out[idx] = bfs(src[k * 128 + n]);
}

// ---- fused q-projection + qk/cb precompute. grid 64 (one block per c).
__global__ __launch_bounds__(256) void qkf_kernel(
    const float* __restrict__ ctx, const float* __restrict__ wq,
    const float* __restrict__ bq, const float* __restrict__ wk,
    const float* __restrict__ bk, unsigned short* __restrict__ qkb,
    float* __restrict__ cb)
{
    __shared__ float qrow[128];
    const int c = blockIdx.x, t = threadIdx.x;
    if (t < 128) {
        float s = bq[t];
        for (int k = 0; k < 128; ++k) s += ctx[c * 128 + k] * wq[(size_t)k * 128 + t];
        qrow[t] = s;
    }
    __syncthreads();
#pragma unroll
    for (int i = 0; i < 4; ++i) {
        int idx = t + i * 256;          // 0..1023
        int h = idx >> 7, j = idx & 127;
        const float* wr = wk + (size_t)j * 128 + h * 16;
        const float* qr = qrow + h * 16;
        float s = 0.f;
#pragma unroll
        for (int d = 0; d < 16; ++d) s += qr[d] * wr[d];
        qkb[(size_t)(h * 64 + c) * 128 + j] = bfs(0.25f * s);
    }
    if (t < 8) {
        float s = 0.f;
#pragma unroll
        for (int d = 0; d < 16; ++d) s += qrow[t * 16 + d] * bk[t * 16 + d];
        cb[t * 64 + c] = 0.25f * s;
    }
}

// ------------------- xt(bf16) = x(fp32) @ theta  via MFMA, grid (391, 3)
__global__ __launch_bounds__(256) void xg_kernel(
    const float* __restrict__ x0, const float* __restrict__ x1,
    const float* __restrict__ x2, const unsigned short* __restrict__ thT,
    unsigned short* __restrict__ y, int R)
{
    int m = blockIdx.y;
    const float* X = (m == 0) ? x0 : (m == 1) ? x1 : x2;
    const unsigned short* W = thT + m * 16384;
    unsigned short* Y = y + (size_t)m * R * 128;
    const int w = threadIdx.x >> 6, lane = threadIdx.x & 63;
    const int ln15 = lane & 15, l16 = lane >> 4;
    const int r0 = blockIdx.x * 128 + w * 32;

    f4v acc[2][8];
#pragma unroll
    for (int i = 0; i < 2; ++i)
#pragma unroll
        for (int j = 0; j < 8; ++j) acc[i][j] = (f4v)0.f;

    for (int ks = 0; ks < 4; ++ks) {
        bf8v a[2];
#pragma unroll
        for (int mt = 0; mt < 2; ++mt) {
            int row = r0 + mt * 16 + ln15;
            row = (row < R) ? row : (R - 1);
            const float* xp = X + (size_t)row * 128 + ks * 32 + l16 * 8;
            float4 f0 = *(const float4*)xp;
            float4 f1 = *(const float4*)(xp + 4);
            union { bf8v v; unsigned w[4]; } u;
            u.w[0] = bfp(f0.x, f0.y);
            u.w[1] = bfp(f0.z, f0.w);
            u.w[2] = bfp(f1.x, f1.y);
            u.w[3] = bfp(f1.z, f1.w);
            a[mt] = u.v;
        }
#pragma unroll
        for (int nt = 0; nt < 8; ++nt) {
            bf8v b = *(const bf8v*)(W + (nt * 16 + ln15) * 128 + ks * 32 + l16 * 8);
            acc[0][nt] = MFMA16(a[0], b, acc[0][nt]);
            acc[1][nt] = MFMA16(a[1], b, acc[1][nt]);
        }
    }
#pragma unroll
    for (int mt = 0; mt < 2; ++mt)
#pragma unroll
        for (int reg = 0; reg < 4; ++reg) {
            int row = r0 + mt * 16 + l16 * 4 + reg;
            if (row < R) {
#pragma unroll
                for (int nt = 0; nt < 8; ++nt)
                    Y[(size_t)row * 128 + nt * 16 + ln15] = bfs(acc[mt][nt][reg]);
            }
        }
}

// --------------------------------------------------- CSR build: count (x6)
__global__ __launch_bounds__(256) void count6_kernel(
    const int* e0, const int* e1, const int* e2,
    const int* n0, const int* n1, const int* n2, int* cntbase)
{
    int b = blockIdx.y;
    const int* arr = (b == 0) ? e0 : (b == 1) ? e1 : (b == 2) ? e2
                   : (b == 3) ? n0 : (b == 4) ? n1 : n2;
    int base = (b < 3) ? b * M_EDGES : 3 * M_EDGES + (b - 3) * N_NODES;
    int i = blockIdx.x * 256 + threadIdx.x;
    if (i < E_INC) atomicAdd(cntbase + base + arr[i], 1);
}

// ------------------------------------- CSR build: 6-way scan, 1024 threads
__global__ __launch_bounds__(1024) void scan6_kernel(
    const int* __restrict__ cnts, int* __restrict__ offs)
{
    const int lens[6] = {M_EDGES, M_EDGES, M_EDGES, N_NODES, N_NODES, N_NODES};
    int b = blockIdx.x;
    int cbase = 0, obase = 0;
    for (int i = 0; i < b; ++i) { cbase += lens[i]; obase += lens[i] + 1; }
    const int* cnt = cnts + cbase;
    int* off = offs + obase;
    const int len = lens[b];
    const int t = threadIdx.x, lane = t & 63, w = t >> 6;   // 16 waves
    __shared__ int wsum[2][16];
    int carry = 0, buf = 0;
    for (int base = 0; base < len; base += 4096, buf ^= 1) {
        int i0 = base + t * 4;
        int v0 = (i0 + 0 < len) ? cnt[i0 + 0] : 0;
        int v1 = (i0 + 1 < len) ? cnt[i0 + 1] : 0;
        int v2 = (i0 + 2 < len) ? cnt[i0 + 2] : 0;
        int v3 = (i0 + 3 < len) ? cnt[i0 + 3] : 0;
        int s = v0 + v1 + v2 + v3;
        int incl = s;
#pragma unroll
        for (int d = 1; d < 64; d <<= 1) {
            int x = __shfl_up(incl, d, 64);
            if (lane >= d) incl += x;
        }
        if (lane == 63) wsum[buf][w] = incl;
        __syncthreads();
        int prefix = carry;
        for (int ww = 0; ww < w; ++ww) prefix += wsum[buf][ww];
        int excl = prefix + incl - s;
        if (i0 + 0 < len) off[i0 + 0] = excl;
        if (i0 + 1 < len) off[i0 + 1] = excl + v0;
        if (i0 + 2 < len) off[i0 + 2] = excl + v0 + v1;
        if (i0 + 3 < len) off[i0 + 3] = excl + v0 + v1 + v2;
#pragma unroll
        for (int ww = 0; ww < 16; ++ww) carry += wsum[buf][ww];
    }
    if (t == 0) off[len] = carry;
}

// --------------------------------------------------- CSR build: fill (x6)
__global__ __launch_bounds__(256) void fill6_kernel(
    const int* e0, const int* e1, const int* e2,
    const int* n0, const int* n1, const int* n2,
    int* cntbase, const int* offbase, int* listbase)
{
    int b = blockIdx.y;
    const int* idx   = (b == 0) ? e0 : (b == 1) ? e1 : (b == 2) ? e2
                     : (b == 3) ? n0 : (b == 4) ? n1 : n2;
    const int* other = (b == 0) ? n0 : (b == 1) ? n1 : (b == 2) ? n2
                     : (b == 3) ? e0 : (b == 4) ? e1 : e2;
    int cb = (b < 3) ? b * M_EDGES : 3 * M_EDGES + (b - 3) * N_NODES;
    int ob = (b < 3) ? b * (M_EDGES + 1) : 3 * (M_EDGES + 1) + (b - 3) * (N_NODES + 1);
    int* cnt = cntbase + cb;
    const int* off = offbase + ob;
    int* list = listbase + (size_t)b * E_INC;
    int i = blockIdx.x * 256 + threadIdx.x;
    if (i >= E_INC) return;
    int e = idx[i];
    int pos = atomicSub(&cnt[e], 1) - 1;
    list[off[e] + pos] = other[i];
}

// ------------------- ebuf[e,:] = mean of xt rows (bf16), grid (2500, 3)
__global__ __launch_bounds__(256) void gedge_kernel(
    const unsigned short* __restrict__ xt,
    const int* __restrict__ listbase, const int* __restrict__ offbase,
    unsigned short* __restrict__ eb)
{
    int mm = blockIdx.y;
    const unsigned short* X = xt + (size_t)mm * N_NODES * 128;
    const int* list = listbase + (size_t)mm * E_INC;
    const int* off = offbase + mm * (M_EDGES + 1);
    unsigned short* E = eb + (size_t)mm * M_EDGES * 128;
    int t = blockIdx.x * 256 + threadIdx.x;
    int e = t >> 5, lane = t & 31;
    if (e >= M_EDGES) return;
    int s = off[e], en = off[e + 1];
    float a0 = 0, a1 = 0, a2 = 0, a3 = 0;
    for (int j = s; j < en; ++j) {
        int n = list[j];
        uint2 v = *(const uint2*)(X + (size_t)n * 128 + lane * 4);
        a0 += __uint_as_float(v.x << 16);
        a1 += __uint_as_float(v.x & 0xFFFF0000u);
        a2 += __uint_as_float(v.y << 16);
        a3 += __uint_as_float(v.y & 0xFFFF0000u);
    }
    float bi = (en > s) ? 1.f / (float)(en - s) : 0.f;
    uint2 o;
    o.x = bfp(a0 * bi, a1 * bi);
    o.y = bfp(a2 * bi, a3 * bi);
    *(uint2*)(E + (size_t)e * 128 + lane * 4) = o;
}

// ------------ rel[n,:] = mean of ebuf rows + bias (bf16), grid (6250, 3)
__global__ __launch_bounds__(256) void gnode_kernel(
    const unsigned short* __restrict__ eb,
    const int* __restrict__ listbase, const int* __restrict__ offbase,
    const float* __restrict__ b0, const float* __restrict__ b1,
    const float* __restrict__ b2, unsigned short* __restrict__ rel)
{
    int mm = blockIdx.y;
    const unsigned short* E = eb + (size_t)mm * M_EDGES * 128;
    const int* list = listbase + (size_t)(3 + mm) * E_INC;
    const int* off = offbase + 3 * (M_EDGES + 1) + mm * (N_NODES + 1);
    const float* bias = (mm == 0) ? b0 : (mm == 1) ? b1 : b2;
    unsigned short* R = rel + (size_t)mm * N_NODES * 128;
    int t = blockIdx.x * 256 + threadIdx.x;
    int n = t >> 5, lane = t & 31;
    if (n >= N_NODES) return;
    int s = off[n], en = off[n + 1];
    float a0 = 0, a1 = 0, a2 = 0, a3 = 0;
    for (int j = s; j < en; ++j) {
        int e = list[j];
        uint2 v = *(const uint2*)(E + (size_t)e * 128 + lane * 4);
        a0 += __uint_as_float(v.x << 16);
        a1 += __uint_as_float(v.x & 0xFFFF0000u);
        a2 += __uint_as_float(v.y << 16);
        a3 += __uint_as_float(v.y & 0xFFFF0000u);
    }
    float di = (en > s) ? 1.f / (float)(en - s) : 0.f;
    uint2 o;
    o.x = bfp(a0 * di + bias[lane * 4 + 0], a1 * di + bias[lane * 4 + 1]);
    o.y = bfp(a2 * di + bias[lane * 4 + 2], a3 * di + bias[lane * 4 + 3]);
    *(uint2*)(R + (size_t)n * 128 + lane * 4) = o;
}

// ------------------------------- fused attention: grid (256 strips, 4 pairs)
// Pipelined: double-buffered relN staged via global_load_lds (counted vmcnt),
// XOR-swizzled LDS; GEMM1 A-fragments + transpose both read relN from LDS.
__global__ __launch_bounds__(256) void attn_kernel(
    const unsigned short* __restrict__ rel, const unsigned short* __restrict__ qkb,
    const float* __restrict__ cb, float* __restrict__ PRpart, float* __restrict__ lpart)
{
    // relN: [buf][64 rows x 256B] row-major, byte ^= ((row&7)<<4) (source-side swz)
    // relTb: relT[j][r] 128x64 bf16, row stride 128B, byte ^= ((j&7)<<4)
    // Plb:   Pl[hc][r]  128x64 bf16, row stride 128B, byte ^= ((hc&7)<<4)
    __shared__ __align__(16) unsigned char relN[2][16384];
    __shared__ __align__(16) unsigned char relTb[16384];
    __shared__ __align__(16) unsigned char Plb[16384];

    const int strip = blockIdx.x, pair = blockIdx.y;
    const int t = threadIdx.x, w = t >> 6, lane = t & 63;
    const int ln15 = lane & 15, l16 = lane >> 4;
    const int aswz = (ln15 & 7) << 4;

    bf8v bq[2][4];
#pragma unroll
    for (int nt = 0; nt < 2; ++nt)
#pragma unroll
        for (int ks = 0; ks < 4; ++ks)
            bq[nt][ks] = *(const bf8v*)(qkb +
                (size_t)(pair * 128 + w * 32 + nt * 16 + ln15) * 128 + ks * 32 + l16 * 8);
    float cbr[2];
#pragma unroll
    for (int nt = 0; nt < 2; ++nt)
        cbr[nt] = cb[pair * 128 + w * 32 + nt * 16 + ln15];

    f4v pr[2][8];
#pragma unroll
    for (int i = 0; i < 2; ++i)
#pragma unroll
        for (int j = 0; j < 8; ++j) pr[i][j] = (f4v)0.f;
    float lacc[2] = {0.f, 0.f};

    const int r0s = strip * SROWS;
    const int rend = (r0s + SROWS < R_REL) ? (r0s + SROWS) : R_REL;
    const int nchunk = (rend - r0s + 63) >> 6;

    // stage one 64-row chunk (16 KB) into relN[b]: 4 gll/wave, coalesced 1KB each.
    // global source pre-swizzled so swizzled LDS reads see rel[row][col].
    auto stage = [&](int base, int b) {
#pragma unroll
        for (int k = 0; k < 4; ++k) {
            int o = k * 4096 + w * 1024 + lane * 16;       // linear LDS byte offset
            int rr = o >> 8;                                // row 0..63
            int cbyte = (o & 255) ^ ((rr & 7) << 4);        // inverse-swz source col
            gload16(rel + (size_t)(base + rr) * 128 + (cbyte >> 1),
                    &relN[b][k * 4096 + w * 1024]);
        }
    };

    stage(r0s, 0);
    int cur = 0;
    for (int c = 0; c < nchunk; ++c) {
        const int base = r0s + c * 64;
        const int nvalid = rend - base;

        if (c + 1 < nchunk) {
            stage(base + 64, cur ^ 1);
            __builtin_amdgcn_sched_barrier(0);
            asm volatile("s_waitcnt vmcnt(4)" ::: "memory");   // chunk c landed
        } else {
            __builtin_amdgcn_sched_barrier(0);
            asm volatile("s_waitcnt vmcnt(0)" ::: "memory");
        }
        __builtin_amdgcn_sched_barrier(0);
        __builtin_amdgcn_s_barrier();          // B1: data visible; prev GEMM2 done
        __builtin_amdgcn_sched_barrier(0);

        const unsigned char* RN = relN[cur];

        // ---- transpose relN -> relTb (LDS->LDS) ----
#pragma unroll
        for (int a2 = 0; a2 < 2; ++a2) {
            int idx = t + a2 * 256;
            int rp = idx & 31, jg = idx >> 5;
            int r2 = rp * 2;
            uint4 A = *(const uint4*)(RN + r2 * 256 + ((jg * 16) ^ ((r2 & 7) << 4)));
            uint4 B = *(const uint4*)(RN + (r2 + 1) * 256 + ((jg * 16) ^ (((r2 + 1) & 7) << 4)));
            unsigned aw[4] = {A.x, A.y, A.z, A.w};
            unsigned bw[4] = {B.x, B.y, B.z, B.w};
#pragma unroll
            for (int jj = 0; jj < 4; ++jj) {
                int j0 = jg * 8 + jj * 2;                   // j0&7 == jj*2
                *(unsigned*)(relTb + j0 * 128 + ((rp * 4) ^ ((jj * 2) << 4))) =
                    (aw[jj] & 0xFFFFu) | (bw[jj] << 16);
                *(unsigned*)(relTb + (j0 + 1) * 128 + ((rp * 4) ^ ((jj * 2 + 1) << 4))) =
                    (aw[jj] >> 16) | (bw[jj] & 0xFFFF0000u);
            }
        }

        // ---- GEMM1: S[r, hc], A-fragments from relN (LDS) ----
        f4v sc[4][2];
#pragma unroll
        for (int i = 0; i < 4; ++i) { sc[i][0] = (f4v)0.f; sc[i][1] = (f4v)0.f; }
#pragma unroll
        for (int ks = 0; ks < 4; ++ks) {
            bf8v a[4];
#pragma unroll
            for (int mt = 0; mt < 4; ++mt)
                a[mt] = *(const bf8v*)(RN + (mt * 16 + ln15) * 256 +
                                       ((ks * 64 + l16 * 16) ^ aswz));
#pragma unroll
            for (int mt = 0; mt < 4; ++mt) {
                sc[mt][0] = MFMA16(a[mt], bq[0][ks], sc[mt][0]);
                sc[mt][1] = MFMA16(a[mt], bq[1][ks], sc[mt][1]);
            }
        }

        // ---- exp + mask + Pl writes + l ----
        bool full = (nvalid >= 64);
#pragma unroll
        for (int nt = 0; nt < 2; ++nt) {
            float ls = 0.f;
#pragma unroll
            for (int mt = 0; mt < 4; ++mt) {
                float pv[4];
#pragma unroll
                for (int reg = 0; reg < 4; ++reg) {
                    int rl = mt * 16 + l16 * 4 + reg;
                    float p = __expf(sc[mt][nt][reg] + cbr[nt]);
                    if (!full && rl >= nvalid) p = 0.f;
                    ls += p;
                    pv[reg] = p;
                }
                int hc = w * 32 + nt * 16 + ln15;           // hc&7 == ln15&7
                int pb = hc * 128 + ((mt * 32 + l16 * 8) ^ aswz);
                *(uint2*)(Plb + pb) = make_uint2(bfp(pv[0], pv[1]), bfp(pv[2], pv[3]));
            }
            ls += __shfl_xor(ls, 16, 64);
            ls += __shfl_xor(ls, 32, 64);
            lacc[nt] += ls;
        }

        asm volatile("s_waitcnt lgkmcnt(0)" ::: "memory");
        __builtin_amdgcn_sched_barrier(0);
        __builtin_amdgcn_s_barrier();          // B2: relTb/Plb visible
        __builtin_amdgcn_sched_barrier(0);

        // ---- GEMM2: PR[hc, j] += P^T @ rel ----
#pragma unroll
        for (int ks = 0; ks < 2; ++ks) {
            bf8v ap[2];
#pragma unroll
            for (int mt = 0; mt < 2; ++mt) {
                int hc = w * 32 + mt * 16 + ln15;
                ap[mt] = *(const bf8v*)(Plb + hc * 128 + ((ks * 64 + l16 * 16) ^ aswz));
            }
#pragma unroll
            for (int nt = 0; nt < 8; ++nt) {
                int j = nt * 16 + ln15;
                bf8v b = *(const bf8v*)(relTb + j * 128 + ((ks * 64 + l16 * 16) ^ aswz));
                pr[0][nt] = MFMA16(ap[0], b, pr[0][nt]);
                pr[1][nt] = MFMA16(ap[1], b, pr[1][nt]);
            }
        }
        cur ^= 1;
    }

    // ---- write partials ----
    float* PB = PRpart + (size_t)(pair * STRIPS + strip) * 128 * 128;
#pragma unroll
    for (int mt = 0; mt < 2; ++mt)
#pragma unroll
        for (int reg = 0; reg < 4; ++reg) {
            int hcl = w * 32 + mt * 16 + l16 * 4 + reg;
#pragma unroll
            for (int nt = 0; nt < 8; ++nt)
                PB[hcl * 128 + nt * 16 + ln15] = pr[mt][nt][reg];
        }
    if (lane < 16) {
        float* LB = lpart + (size_t)(pair * STRIPS + strip) * 128;
        LB[w * 32 + ln15] = lacc[0];
        LB[w * 32 + 16 + ln15] = lacc[1];
    }
}

// ---------------- reduce: PRsum -> o_norm -> osum (atomic), grid 512
__global__ __launch_bounds__(256) void reduce_kernel(
    const float* __restrict__ PRpart, const float* __restrict__ lpart,
    const float* __restrict__ wv, const float* __restrict__ bv,
    float* __restrict__ osum)
{
    int hc = blockIdx.x;
    int pair = hc >> 7, hcl = hc & 127, h = hc >> 6;
    __shared__ float PS[128];
    __shared__ float LL[129];
    int t = threadIdx.x;
    if (t < 128) {
        float s = 0.f;
        const float* p = PRpart + ((size_t)(pair * STRIPS) * 128 + hcl) * 128 + t;
        for (int st = 0; st < STRIPS; ++st) s += p[(size_t)st * 128 * 128];
        PS[t] = s;
    } else {
        int idx = t - 128;   // 0..127, each covers 2 strips
        LL[idx] = lpart[(size_t)(pair * STRIPS + idx) * 128 + hcl]
                + lpart[(size_t)(pair * STRIPS + idx + 128) * 128 + hcl];
    }
    __syncthreads();
    if (t == 0) {
        float l = 0.f;
        for (int st = 0; st < 128; ++st) l += LL[st];
        LL[128] = l;
    }
    __syncthreads();
    if (t < 16) {
        float o = 0.f;
        for (int j = 0; j < 128; ++j) o += PS[j] * wv[(size_t)j * 128 + h * 16 + t];
        float on = o / LL[128] + bv[h * 16 + t];
        atomicAdd(&osum[h * 16 + t], on);
    }
}

// --- u[d] = (sum_c ctx[c,d] + (osum@wo)[d]/64 + bo[d]) / 65
__global__ __launch_bounds__(128) void user_kernel(
    const float* __restrict__ ctx, const float* __restrict__ osum,
    const float* __restrict__ wo, const float* __restrict__ bo,
    float* __restrict__ u)
{
    __shared__ float os[128];
    int d = threadIdx.x;
    os[d] = osum[d];
    __syncthreads();
    float cs = 0.f;
    for (int cc = 0; cc < 64; ++cc) cs += ctx[cc * 128 + d];
    float ow = 0.f;
    for (int j = 0; j < 128; ++j) ow += os[j] * wo[j * 128 + d];
    u[d] = (cs + ow * (1.f / 64.f) + bo[d]) * (1.f / 65.f);
}

// --------------------------------- out[j] = u @ w_rec[:,j] + b_rec[j]
__global__ __launch_bounds__(256) void rec_kernel(
    const float* __restrict__ u, const float* __restrict__ wrec,
    const float* __restrict__ brec, float* __restrict__ out)
{
    __shared__ float ul[128];
    if (threadIdx.x < 128) ul[threadIdx.x] = u[threadIdx.x];
    __syncthreads();
    int j = blockIdx.x * 256 + threadIdx.x;
    if (j >= NE_OUT) return;
    float a0 = brec[j], a1 = 0.f, a2 = 0.f, a3 = 0.f;
#pragma unroll 4
    for (int d = 0; d < 128; d += 4) {
        a0 += ul[d + 0] * wrec[(size_t)(d + 0) * NE_OUT + j];
        a1 += ul[d + 1] * wrec[(size_t)(d + 1) * NE_OUT + j];
        a2 += ul[d + 2] * wrec[(size_t)(d + 2) * NE_OUT + j];
        a3 += ul[d + 3] * wrec[(size_t)(d + 3) * NE_OUT + j];
    }
    out[j] = (a0 + a1) + (a2 + a3);
}

extern "C" void kernel_launch(void* const* d_in, const int* in_sizes, int n_in,
                              void* d_out, int out_size, void* d_ws, size_t ws_size,
                              hipStream_t stream)
{
    const float* ctx  = (const float*)d_in[9];
    const float* wq = (const float*)d_in[10];
    const float* bq = (const float*)d_in[11];
    const float* wk = (const float*)d_in[12];
    const float* bk = (const float*)d_in[13];
    const float* wv = (const float*)d_in[14];
    const float* bv = (const float*)d_in[15];
    const float* wo = (const float*)d_in[16];
    const float* bo = (const float*)d_in[17];
    const float* wrec = (const float*)d_in[18];
    const float* brec = (const float*)d_in[19];
    const int* node0 = (const int*)d_in[20];
    const int* edge0 = (const int*)d_in[21];
    const int* node1 = (const int*)d_in[22];
    const int* edge1 = (const int*)d_in[23];
    const int* node2 = (const int*)d_in[24];
    const int* edge2 = (const int*)d_in[25];
    float* out = (float*)d_out;

    char* ws = (char*)d_ws;
    size_t off = 0;
    auto alloc = [&](size_t nbytes) {
        void* p = ws + off;
        off += (nbytes + 255) & ~(size_t)255;
        return p;
    };
    unsigned short* rel  = (unsigned short*)alloc((size_t)R_REL * 128 * 2);
    unsigned short* xt   = (unsigned short*)alloc((size_t)3 * N_NODES * 128 * 2);
    unsigned short* eb   = (unsigned short*)alloc((size_t)3 * M_EDGES * 128 * 2);
    float* PRpart = (float*)alloc((size_t)4 * STRIPS * 128 * 128 * 4);   // 67 MB
    float* lpart  = (float*)alloc((size_t)4 * STRIPS * 128 * 4);
    unsigned short* qkb = (unsigned short*)alloc(512 * 128 * 2);
    float* cbv    = (float*)alloc(512 * 4);
    unsigned short* thT = (unsigned short*)alloc(3 * 16384 * 2);
    int* cntbase  = (int*)alloc((size_t)(3 * M_EDGES + 3 * N_NODES + 128) * 4); // + osum
    float* osum   = (float*)(cntbase + 3 * M_EDGES + 3 * N_NODES);
    int* offbase  = (int*)alloc((size_t)(3 * (M_EDGES + 1) + 3 * (N_NODES + 1)) * 4);
    int* listbase = (int*)alloc((size_t)6 * E_INC * 4);
    float* u      = (float*)alloc(128 * 4);
    (void)ws_size; (void)in_sizes; (void)n_in; (void)out_size;

    // 1. zero cnt + osum (contiguous)
    {
        int nwords = 3 * M_EDGES + 3 * N_NODES + 128;   // 210128, /4 = 52532
        zero_kernel<<<(nwords / 4 + 255) / 256, 256, 0, stream>>>((float4*)cntbase, nwords / 4);
    }
    // 2-4. CSR build
    const int gE = (E_INC + 255) / 256;
    count6_kernel<<<dim3(gE, 6), 256, 0, stream>>>(edge0, edge1, edge2, node0, node1, node2, cntbase);
    scan6_kernel<<<6, 1024, 0, stream>>>(cntbase, offbase);
    fill6_kernel<<<dim3(gE, 6), 256, 0, stream>>>(edge0, edge1, edge2, node0, node1, node2,
                                                  cntbase, offbase, listbase);
    // 5. weight conversion (theta^T bf16)
    wconv_kernel<<<192, 256, 0, stream>>>((const float*)d_in[1], (const float*)d_in[4],
                                          (const float*)d_in[7], thT);
    // 6. fused q projection + qk/cb precompute
    qkf_kernel<<<64, 256, 0, stream>>>(ctx, wq, bq, wk, bk, qkb, cbv);
    // 7. xt = x @ theta (bf16 MFMA), all modalities
    xg_kernel<<<dim3((N_NODES + 127) / 128, 3), 256, 0, stream>>>(
        (const float*)d_in[0], (const float*)d_in[3], (const float*)d_in[6], thT, xt, N_NODES);
    // 8-9. gathers
    gedge_kernel<<<dim3(M_EDGES * 32 / 256, 3), 256, 0, stream>>>(xt, listbase, offbase, eb);
    gnode_kernel<<<dim3(N_NODES * 32 / 256, 3), 256, 0, stream>>>(
        eb, listbase, offbase, (const float*)d_in[2], (const float*)d_in[5],
        (const float*)d_in[8], rel);
    // 10-11. fused attention + reduce
    attn_kernel<<<dim3(STRIPS, 4), 256, 0, stream>>>(rel, qkb, cbv, PRpart, lpart);
    reduce_kernel<<<512, 256, 0, stream>>>(PRpart, lpart, wv, bv, osum);
    // 12-13. user repr + final scores
    user_kernel<<<1, 128, 0, stream>>>(ctx, osum, wo, bo, u);
    rec_kernel<<<(NE_OUT + 255) / 256, 256, 0, stream>>>(u, wrec, brec, out);
}

// Round 3
// 563.331 us; speedup vs baseline: 1.1474x; 1.0620x over previous
//
#include <hip/hip_runtime.h>
#include <hip/hip_bf16.h>

// Problem constants (fixed by the reference setup_inputs)
constexpr int N_NODES = 50000;
constexpr int M_EDGES = 20000;
constexpr int E_INC   = 200000;
constexpr int H_HEADS = 8;
constexpr int C_CTX   = 64;
constexpr int NE_OUT  = 200000;
constexpr int R_REL   = 3 * N_NODES; // 150000

constexpr int STRIPS  = 128;         // 128x4 = 512 blocks = 2 blocks/CU, single pass
constexpr int SROWS   = 1172;        // ceil(150000/128)

typedef short bf8v __attribute__((ext_vector_type(8)));   // 8 bf16 (4 VGPRs)
typedef float f4v  __attribute__((ext_vector_type(4)));   // 4 fp32 acc
#define MFMA16(a, b, c) __builtin_amdgcn_mfma_f32_16x16x32_bf16(a, b, c, 0, 0, 0)

// fp32 -> bf16 (RNE) scalar; compiler emits v_cvt equivalents
__device__ __forceinline__ unsigned short bfs(float f) {
    union { __hip_bfloat16 b; unsigned short s; } u;
    u.b = __float2bfloat16(f);
    return u.s;
}
// packed pair: low short = lo, high short = hi (v_cvt_pk_bf16_f32)
__device__ __forceinline__ unsigned bfp(float lo, float hi) {
    union { __hip_bfloat162 b; unsigned u; } v;
    v.b = __float22bfloat162_rn(make_float2(lo, hi));
    return v.u;
}

// async global->LDS 16B per lane. LDS dest = wave-uniform base + lane*16 (HW).
__device__ __forceinline__ void gload16(const void* g, const void* l) {
    __builtin_amdgcn_global_load_lds(
        (const __attribute__((address_space(1))) void*)(unsigned long long)(size_t)g,
        (__attribute__((address_space(3))) void*)(unsigned)(size_t)l,
        16, 0, 0);
}

// ---------------------------------------------------------------- zero fill
__global__ __launch_bounds__(256) void zero_kernel(float4* p, int n4) {
    int i = blockIdx.x * 256 + threadIdx.x;
    if (i < n4) p[i] = make_float4(0.f, 0.f, 0.f, 0.f);
}

// ------------------------------------------- theta -> bf16 transposed [n][k]
__global__ __launch_bounds__(256) void wconv_kernel(
    const float* __restrict__ t0, const float* __restrict__ t1,
    const float* __restrict__ t2, unsigned short* __restrict__ out)
{
    int idx = blockIdx.x * 256 + threadIdx.x;   // 0..49151
    int m = idx >> 14, p = idx & 16383;
    int n = p >> 7, k = p & 127;
    const float* src = (m == 0) ? t0 : (m == 1) ? t1 : t2;
    out[idx] = bfs(src[k * 128 + n]);
}

// ---- fused q-projection + qk/cb precompute. grid 64 (one block per c).
__global__ __launch_bounds__(256) void qkf_kernel(
    const float* __restrict__ ctx, const float* __restrict__ wq,
    const float* __restrict__ bq, const float* __restrict__ wk,
    const float* __restrict__ bk, unsigned short* __restrict__ qkb,
    float* __restrict__ cb)
{
    __shared__ float qrow[128];
    const int c = blockIdx.x, t = threadIdx.x;
    if (t < 128) {
        float s = bq[t];
        for (int k = 0; k < 128; ++k) s += ctx[c * 128 + k] * wq[(size_t)k * 128 + t];
        qrow[t] = s;
    }
    __syncthreads();
#pragma unroll
    for (int i = 0; i < 4; ++i) {
        int idx = t + i * 256;          // 0..1023
        int h = idx >> 7, j = idx & 127;
        const float* wr = wk + (size_t)j * 128 + h * 16;
        const float* qr = qrow + h * 16;
        float s = 0.f;
#pragma unroll
        for (int d = 0; d < 16; ++d) s += qr[d] * wr[d];
        qkb[(size_t)(h * 64 + c) * 128 + j] = bfs(0.25f * s);
    }
    if (t < 8) {
        float s = 0.f;
#pragma unroll
        for (int d = 0; d < 16; ++d) s += qrow[t * 16 + d] * bk[t * 16 + d];
        cb[t * 64 + c] = 0.25f * s;
    }
}

// ------------------- xt(bf16) = x(fp32) @ theta  via MFMA, grid (391, 3)
__global__ __launch_bounds__(256) void xg_kernel(
    const float* __restrict__ x0, const float* __restrict__ x1,
    const float* __restrict__ x2, const unsigned short* __restrict__ thT,
    unsigned short* __restrict__ y, int R)
{
    int m = blockIdx.y;
    const float* X = (m == 0) ? x0 : (m == 1) ? x1 : x2;
    const unsigned short* W = thT + m * 16384;
    unsigned short* Y = y + (size_t)m * R * 128;
    const int w = threadIdx.x >> 6, lane = threadIdx.x & 63;
    const int ln15 = lane & 15, l16 = lane >> 4;
    const int r0 = blockIdx.x * 128 + w * 32;

    f4v acc[2][8];
#pragma unroll
    for (int i = 0; i < 2; ++i)
#pragma unroll
        for (int j = 0; j < 8; ++j) acc[i][j] = (f4v)0.f;

    for (int ks = 0; ks < 4; ++ks) {
        bf8v a[2];
#pragma unroll
        for (int mt = 0; mt < 2; ++mt) {
            int row = r0 + mt * 16 + ln15;
            row = (row < R) ? row : (R - 1);
            const float* xp = X + (size_t)row * 128 + ks * 32 + l16 * 8;
            float4 f0 = *(const float4*)xp;
            float4 f1 = *(const float4*)(xp + 4);
            union { bf8v v; unsigned w[4]; } u;
            u.w[0] = bfp(f0.x, f0.y);
            u.w[1] = bfp(f0.z, f0.w);
            u.w[2] = bfp(f1.x, f1.y);
            u.w[3] = bfp(f1.z, f1.w);
            a[mt] = u.v;
        }
#pragma unroll
        for (int nt = 0; nt < 8; ++nt) {
            bf8v b = *(const bf8v*)(W + (nt * 16 + ln15) * 128 + ks * 32 + l16 * 8);
            acc[0][nt] = MFMA16(a[0], b, acc[0][nt]);
            acc[1][nt] = MFMA16(a[1], b, acc[1][nt]);
        }
    }
#pragma unroll
    for (int mt = 0; mt < 2; ++mt)
#pragma unroll
        for (int reg = 0; reg < 4; ++reg) {
            int row = r0 + mt * 16 + l16 * 4 + reg;
            if (row < R) {
#pragma unroll
                for (int nt = 0; nt < 8; ++nt)
                    Y[(size_t)row * 128 + nt * 16 + ln15] = bfs(acc[mt][nt][reg]);
            }
        }
}

// --------------------------------------------------- CSR build: count (x6)
__global__ __launch_bounds__(256) void count6_kernel(
    const int* e0, const int* e1, const int* e2,
    const int* n0, const int* n1, const int* n2, int* cntbase)
{
    int b = blockIdx.y;
    const int* arr = (b == 0) ? e0 : (b == 1) ? e1 : (b == 2) ? e2
                   : (b == 3) ? n0 : (b == 4) ? n1 : n2;
    int base = (b < 3) ? b * M_EDGES : 3 * M_EDGES + (b - 3) * N_NODES;
    int i = blockIdx.x * 256 + threadIdx.x;
    if (i < E_INC) atomicAdd(cntbase + base + arr[i], 1);
}

// ------------------------------------- CSR build: 6-way scan, 1024 threads
__global__ __launch_bounds__(1024) void scan6_kernel(
    const int* __restrict__ cnts, int* __restrict__ offs)
{
    const int lens[6] = {M_EDGES, M_EDGES, M_EDGES, N_NODES, N_NODES, N_NODES};
    int b = blockIdx.x;
    int cbase = 0, obase = 0;
    for (int i = 0; i < b; ++i) { cbase += lens[i]; obase += lens[i] + 1; }
    const int* cnt = cnts + cbase;
    int* off = offs + obase;
    const int len = lens[b];
    const int t = threadIdx.x, lane = t & 63, w = t >> 6;   // 16 waves
    __shared__ int wsum[2][16];
    int carry = 0, buf = 0;
    for (int base = 0; base < len; base += 4096, buf ^= 1) {
        int i0 = base + t * 4;
        int v0 = (i0 + 0 < len) ? cnt[i0 + 0] : 0;
        int v1 = (i0 + 1 < len) ? cnt[i0 + 1] : 0;
        int v2 = (i0 + 2 < len) ? cnt[i0 + 2] : 0;
        int v3 = (i0 + 3 < len) ? cnt[i0 + 3] : 0;
        int s = v0 + v1 + v2 + v3;
        int incl = s;
#pragma unroll
        for (int d = 1; d < 64; d <<= 1) {
            int x = __shfl_up(incl, d, 64);
            if (lane >= d) incl += x;
        }
        if (lane == 63) wsum[buf][w] = incl;
        __syncthreads();
        int prefix = carry;
        for (int ww = 0; ww < w; ++ww) prefix += wsum[buf][ww];
        int excl = prefix + incl - s;
        if (i0 + 0 < len) off[i0 + 0] = excl;
        if (i0 + 1 < len) off[i0 + 1] = excl + v0;
        if (i0 + 2 < len) off[i0 + 2] = excl + v0 + v1;
        if (i0 + 3 < len) off[i0 + 3] = excl + v0 + v1 + v2;
#pragma unroll
        for (int ww = 0; ww < 16; ++ww) carry += wsum[buf][ww];
    }
    if (t == 0) off[len] = carry;
}

// --------------------------------------------------- CSR build: fill (x6)
__global__ __launch_bounds__(256) void fill6_kernel(
    const int* e0, const int* e1, const int* e2,
    const int* n0, const int* n1, const int* n2,
    int* cntbase, const int* offbase, int* listbase)
{
    int b = blockIdx.y;
    const int* idx   = (b == 0) ? e0 : (b == 1) ? e1 : (b == 2) ? e2
                     : (b == 3) ? n0 : (b == 4) ? n1 : n2;
    const int* other = (b == 0) ? n0 : (b == 1) ? n1 : (b == 2) ? n2
                     : (b == 3) ? e0 : (b == 4) ? e1 : e2;
    int cb = (b < 3) ? b * M_EDGES : 3 * M_EDGES + (b - 3) * N_NODES;
    int ob = (b < 3) ? b * (M_EDGES + 1) : 3 * (M_EDGES + 1) + (b - 3) * (N_NODES + 1);
    int* cnt = cntbase + cb;
    const int* off = offbase + ob;
    int* list = listbase + (size_t)b * E_INC;
    int i = blockIdx.x * 256 + threadIdx.x;
    if (i >= E_INC) return;
    int e = idx[i];
    int pos = atomicSub(&cnt[e], 1) - 1;
    list[off[e] + pos] = other[i];
}

// ---- 8-float accumulate of a uint4 (8 bf16)
#define ACC8(v) do { \
    a0 += __uint_as_float((v).x << 16); a1 += __uint_as_float((v).x & 0xFFFF0000u); \
    a2 += __uint_as_float((v).y << 16); a3 += __uint_as_float((v).y & 0xFFFF0000u); \
    a4 += __uint_as_float((v).z << 16); a5 += __uint_as_float((v).z & 0xFFFF0000u); \
    a6 += __uint_as_float((v).w << 16); a7 += __uint_as_float((v).w & 0xFFFF0000u); } while (0)

// ------------------- ebuf[e,:] = mean of xt rows (bf16), grid (1250, 3)
// 16 lanes per edge (uint4 = 16B/lane), degree loop unrolled x4 for MLP.
__global__ __launch_bounds__(256) void gedge_kernel(
    const unsigned short* __restrict__ xt,
    const int* __restrict__ listbase, const int* __restrict__ offbase,
    unsigned short* __restrict__ eb)
{
    int mm = blockIdx.y;
    const unsigned short* X = xt + (size_t)mm * N_NODES * 128;
    const int* list = listbase + (size_t)mm * E_INC;
    const int* off = offbase + mm * (M_EDGES + 1);
    unsigned short* Eo = eb + (size_t)mm * M_EDGES * 128;
    int t = blockIdx.x * 256 + threadIdx.x;
    int e = t >> 4, lane = t & 15;
    if (e >= M_EDGES) return;
    int s = off[e], en = off[e + 1];
    float a0 = 0, a1 = 0, a2 = 0, a3 = 0, a4 = 0, a5 = 0, a6 = 0, a7 = 0;
    int j = s;
    for (; j + 4 <= en; j += 4) {
        int n0 = list[j], n1 = list[j + 1], n2 = list[j + 2], n3 = list[j + 3];
        uint4 v0 = *(const uint4*)(X + (size_t)n0 * 128 + lane * 8);
        uint4 v1 = *(const uint4*)(X + (size_t)n1 * 128 + lane * 8);
        uint4 v2 = *(const uint4*)(X + (size_t)n2 * 128 + lane * 8);
        uint4 v3 = *(const uint4*)(X + (size_t)n3 * 128 + lane * 8);
        ACC8(v0); ACC8(v1); ACC8(v2); ACC8(v3);
    }
    for (; j < en; ++j) {
        int n = list[j];
        uint4 v = *(const uint4*)(X + (size_t)n * 128 + lane * 8);
        ACC8(v);
    }
    float bi = (en > s) ? 1.f / (float)(en - s) : 0.f;
    uint4 o;
    o.x = bfp(a0 * bi, a1 * bi);
    o.y = bfp(a2 * bi, a3 * bi);
    o.z = bfp(a4 * bi, a5 * bi);
    o.w = bfp(a6 * bi, a7 * bi);
    *(uint4*)(Eo + (size_t)e * 128 + lane * 8) = o;
}

// ------------ rel[n,:] = mean of ebuf rows + bias (bf16), grid (3125, 3)
__global__ __launch_bounds__(256) void gnode_kernel(
    const unsigned short* __restrict__ eb,
    const int* __restrict__ listbase, const int* __restrict__ offbase,
    const float* __restrict__ b0, const float* __restrict__ b1,
    const float* __restrict__ b2, unsigned short* __restrict__ rel)
{
    int mm = blockIdx.y;
    const unsigned short* E = eb + (size_t)mm * M_EDGES * 128;
    const int* list = listbase + (size_t)(3 + mm) * E_INC;
    const int* off = offbase + 3 * (M_EDGES + 1) + mm * (N_NODES + 1);
    const float* bias = (mm == 0) ? b0 : (mm == 1) ? b1 : b2;
    unsigned short* R = rel + (size_t)mm * N_NODES * 128;
    int t = blockIdx.x * 256 + threadIdx.x;
    int n = t >> 4, lane = t & 15;
    if (n >= N_NODES) return;
    int s = off[n], en = off[n + 1];
    float a0 = 0, a1 = 0, a2 = 0, a3 = 0, a4 = 0, a5 = 0, a6 = 0, a7 = 0;
    int j = s;
    for (; j + 4 <= en; j += 4) {
        int e0 = list[j], e1 = list[j + 1], e2 = list[j + 2], e3 = list[j + 3];
        uint4 v0 = *(const uint4*)(E + (size_t)e0 * 128 + lane * 8);
        uint4 v1 = *(const uint4*)(E + (size_t)e1 * 128 + lane * 8);
        uint4 v2 = *(const uint4*)(E + (size_t)e2 * 128 + lane * 8);
        uint4 v3 = *(const uint4*)(E + (size_t)e3 * 128 + lane * 8);
        ACC8(v0); ACC8(v1); ACC8(v2); ACC8(v3);
    }
    for (; j < en; ++j) {
        int e = list[j];
        uint4 v = *(const uint4*)(E + (size_t)e * 128 + lane * 8);
        ACC8(v);
    }
    float di = (en > s) ? 1.f / (float)(en - s) : 0.f;
    uint4 o;
    o.x = bfp(a0 * di + bias[lane * 8 + 0], a1 * di + bias[lane * 8 + 1]);
    o.y = bfp(a2 * di + bias[lane * 8 + 2], a3 * di + bias[lane * 8 + 3]);
    o.z = bfp(a4 * di + bias[lane * 8 + 4], a5 * di + bias[lane * 8 + 5]);
    o.w = bfp(a6 * di + bias[lane * 8 + 6], a7 * di + bias[lane * 8 + 7]);
    *(uint4*)(R + (size_t)n * 128 + lane * 8) = o;
}

// ------------------------------- fused attention: grid (128 strips, 4 pairs)
// Pipelined: double-buffered relN staged via global_load_lds (counted vmcnt),
// XOR-swizzled LDS; GEMM1 A-fragments + transpose both read relN from LDS.
__global__ __launch_bounds__(256) void attn_kernel(
    const unsigned short* __restrict__ rel, const unsigned short* __restrict__ qkb,
    const float* __restrict__ cb, float* __restrict__ PRpart, float* __restrict__ lpart)
{
    __shared__ __align__(16) unsigned char relN[2][16384];
    __shared__ __align__(16) unsigned char relTb[16384];
    __shared__ __align__(16) unsigned char Plb[16384];

    const int strip = blockIdx.x, pair = blockIdx.y;
    const int t = threadIdx.x, w = t >> 6, lane = t & 63;
    const int ln15 = lane & 15, l16 = lane >> 4;
    const int aswz = (ln15 & 7) << 4;

    bf8v bq[2][4];
#pragma unroll
    for (int nt = 0; nt < 2; ++nt)
#pragma unroll
        for (int ks = 0; ks < 4; ++ks)
            bq[nt][ks] = *(const bf8v*)(qkb +
                (size_t)(pair * 128 + w * 32 + nt * 16 + ln15) * 128 + ks * 32 + l16 * 8);
    float cbr[2];
#pragma unroll
    for (int nt = 0; nt < 2; ++nt)
        cbr[nt] = cb[pair * 128 + w * 32 + nt * 16 + ln15];

    f4v pr[2][8];
#pragma unroll
    for (int i = 0; i < 2; ++i)
#pragma unroll
        for (int j = 0; j < 8; ++j) pr[i][j] = (f4v)0.f;
    float lacc[2] = {0.f, 0.f};

    const int r0s = strip * SROWS;
    const int rend = (r0s + SROWS < R_REL) ? (r0s + SROWS) : R_REL;
    const int nchunk = (rend - r0s + 63) >> 6;

    auto stage = [&](int base, int b) {
#pragma unroll
        for (int k = 0; k < 4; ++k) {
            int o = k * 4096 + w * 1024 + lane * 16;       // linear LDS byte offset
            int rr = o >> 8;                                // row 0..63
            int cbyte = (o & 255) ^ ((rr & 7) << 4);        // inverse-swz source col
            gload16(rel + (size_t)(base + rr) * 128 + (cbyte >> 1),
                    &relN[b][k * 4096 + w * 1024]);
        }
    };

    stage(r0s, 0);
    int cur = 0;
    for (int c = 0; c < nchunk; ++c) {
        const int base = r0s + c * 64;
        const int nvalid = rend - base;

        if (c + 1 < nchunk) {
            stage(base + 64, cur ^ 1);
            __builtin_amdgcn_sched_barrier(0);
            asm volatile("s_waitcnt vmcnt(4)" ::: "memory");   // chunk c landed
        } else {
            __builtin_amdgcn_sched_barrier(0);
            asm volatile("s_waitcnt vmcnt(0)" ::: "memory");
        }
        __builtin_amdgcn_sched_barrier(0);
        __builtin_amdgcn_s_barrier();          // B1: data visible; prev GEMM2 done
        __builtin_amdgcn_sched_barrier(0);

        const unsigned char* RN = relN[cur];

        // ---- transpose relN -> relTb (LDS->LDS) ----
#pragma unroll
        for (int a2 = 0; a2 < 2; ++a2) {
            int idx = t + a2 * 256;
            int rp = idx & 31, jg = idx >> 5;
            int r2 = rp * 2;
            uint4 A = *(const uint4*)(RN + r2 * 256 + ((jg * 16) ^ ((r2 & 7) << 4)));
            uint4 B = *(const uint4*)(RN + (r2 + 1) * 256 + ((jg * 16) ^ (((r2 + 1) & 7) << 4)));
            unsigned aw[4] = {A.x, A.y, A.z, A.w};
            unsigned bw[4] = {B.x, B.y, B.z, B.w};
#pragma unroll
            for (int jj = 0; jj < 4; ++jj) {
                int j0 = jg * 8 + jj * 2;                   // j0&7 == jj*2
                *(unsigned*)(relTb + j0 * 128 + ((rp * 4) ^ ((jj * 2) << 4))) =
                    (aw[jj] & 0xFFFFu) | (bw[jj] << 16);
                *(unsigned*)(relTb + (j0 + 1) * 128 + ((rp * 4) ^ ((jj * 2 + 1) << 4))) =
                    (aw[jj] >> 16) | (bw[jj] & 0xFFFF0000u);
            }
        }

        // ---- GEMM1: S[r, hc], A-fragments from relN (LDS) ----
        f4v sc[4][2];
#pragma unroll
        for (int i = 0; i < 4; ++i) { sc[i][0] = (f4v)0.f; sc[i][1] = (f4v)0.f; }
#pragma unroll
        for (int ks = 0; ks < 4; ++ks) {
            bf8v a[4];
#pragma unroll
            for (int mt = 0; mt < 4; ++mt)
                a[mt] = *(const bf8v*)(RN + (mt * 16 + ln15) * 256 +
                                       ((ks * 64 + l16 * 16) ^ aswz));
#pragma unroll
            for (int mt = 0; mt < 4; ++mt) {
                sc[mt][0] = MFMA16(a[mt], bq[0][ks], sc[mt][0]);
                sc[mt][1] = MFMA16(a[mt], bq[1][ks], sc[mt][1]);
            }
        }

        // ---- exp + mask + Pl writes + l ----
        bool full = (nvalid >= 64);
#pragma unroll
        for (int nt = 0; nt < 2; ++nt) {
            float ls = 0.f;
#pragma unroll
            for (int mt = 0; mt < 4; ++mt) {
                float pv[4];
#pragma unroll
                for (int reg = 0; reg < 4; ++reg) {
                    int rl = mt * 16 + l16 * 4 + reg;
                    float p = __expf(sc[mt][nt][reg] + cbr[nt]);
                    if (!full && rl >= nvalid) p = 0.f;
                    ls += p;
                    pv[reg] = p;
                }
                int hc = w * 32 + nt * 16 + ln15;           // hc&7 == ln15&7
                int pb = hc * 128 + ((mt * 32 + l16 * 8) ^ aswz);
                *(uint2*)(Plb + pb) = make_uint2(bfp(pv[0], pv[1]), bfp(pv[2], pv[3]));
            }
            ls += __shfl_xor(ls, 16, 64);
            ls += __shfl_xor(ls, 32, 64);
            lacc[nt] += ls;
        }

        asm volatile("s_waitcnt lgkmcnt(0)" ::: "memory");
        __builtin_amdgcn_sched_barrier(0);
        __builtin_amdgcn_s_barrier();          // B2: relTb/Plb visible
        __builtin_amdgcn_sched_barrier(0);

        // ---- GEMM2: PR[hc, j] += P^T @ rel ----
#pragma unroll
        for (int ks = 0; ks < 2; ++ks) {
            bf8v ap[2];
#pragma unroll
            for (int mt = 0; mt < 2; ++mt) {
                int hc = w * 32 + mt * 16 + ln15;
                ap[mt] = *(const bf8v*)(Plb + hc * 128 + ((ks * 64 + l16 * 16) ^ aswz));
            }
#pragma unroll
            for (int nt = 0; nt < 8; ++nt) {
                int j = nt * 16 + ln15;
                bf8v b = *(const bf8v*)(relTb + j * 128 + ((ks * 64 + l16 * 16) ^ aswz));
                pr[0][nt] = MFMA16(ap[0], b, pr[0][nt]);
                pr[1][nt] = MFMA16(ap[1], b, pr[1][nt]);
            }
        }
        cur ^= 1;
    }

    // ---- write partials ----
    float* PB = PRpart + (size_t)(pair * STRIPS + strip) * 128 * 128;
#pragma unroll
    for (int mt = 0; mt < 2; ++mt)
#pragma unroll
        for (int reg = 0; reg < 4; ++reg) {
            int hcl = w * 32 + mt * 16 + l16 * 4 + reg;
#pragma unroll
            for (int nt = 0; nt < 8; ++nt)
                PB[hcl * 128 + nt * 16 + ln15] = pr[mt][nt][reg];
        }
    if (lane < 16) {
        float* LB = lpart + (size_t)(pair * STRIPS + strip) * 128;
        LB[w * 32 + ln15] = lacc[0];
        LB[w * 32 + 16 + ln15] = lacc[1];
    }
}

// ---------------- reduce: PRsum -> o_norm -> osum (atomic), grid 512
__global__ __launch_bounds__(256) void reduce_kernel(
    const float* __restrict__ PRpart, const float* __restrict__ lpart,
    const float* __restrict__ wv, const float* __restrict__ bv,
    float* __restrict__ osum)
{
    int hc = blockIdx.x;
    int pair = hc >> 7, hcl = hc & 127, h = hc >> 6;
    __shared__ float PS[128];
    __shared__ float LL[129];
    int t = threadIdx.x;
    if (t < 128) {
        float s = 0.f;
        const float* p = PRpart + ((size_t)(pair * STRIPS) * 128 + hcl) * 128 + t;
        for (int st = 0; st < STRIPS; ++st) s += p[(size_t)st * 128 * 128];
        PS[t] = s;
    } else {
        int idx = t - 128;   // 0..127, one strip each (STRIPS==128)
        LL[idx] = lpart[(size_t)(pair * STRIPS + idx) * 128 + hcl];
    }
    __syncthreads();
    if (t == 0) {
        float l = 0.f;
        for (int st = 0; st < 128; ++st) l += LL[st];
        LL[128] = l;
    }
    __syncthreads();
    if (t < 16) {
        float o = 0.f;
        for (int j = 0; j < 128; ++j) o += PS[j] * wv[(size_t)j * 128 + h * 16 + t];
        float on = o / LL[128] + bv[h * 16 + t];
        atomicAdd(&osum[h * 16 + t], on);
    }
}

// --- u[d] = (sum_c ctx[c,d] + (osum@wo)[d]/64 + bo[d]) / 65
__global__ __launch_bounds__(128) void user_kernel(
    const float* __restrict__ ctx, const float* __restrict__ osum,
    const float* __restrict__ wo, const float* __restrict__ bo,
    float* __restrict__ u)
{
    __shared__ float os[128];
    int d = threadIdx.x;
    os[d] = osum[d];
    __syncthreads();
    float cs = 0.f;
    for (int cc = 0; cc < 64; ++cc) cs += ctx[cc * 128 + d];
    float ow = 0.f;
    for (int j = 0; j < 128; ++j) ow += os[j] * wo[j * 128 + d];
    u[d] = (cs + ow * (1.f / 64.f) + bo[d]) * (1.f / 65.f);
}

// --------------------------------- out[j] = u @ w_rec[:,j] + b_rec[j]
__global__ __launch_bounds__(256) void rec_kernel(
    const float* __restrict__ u, const float* __restrict__ wrec,
    const float* __restrict__ brec, float* __restrict__ out)
{
    __shared__ float ul[128];
    if (threadIdx.x < 128) ul[threadIdx.x] = u[threadIdx.x];
    __syncthreads();
    int j = blockIdx.x * 256 + threadIdx.x;
    if (j >= NE_OUT) return;
    float a0 = brec[j], a1 = 0.f, a2 = 0.f, a3 = 0.f;
#pragma unroll 4
    for (int d = 0; d < 128; d += 4) {
        a0 += ul[d + 0] * wrec[(size_t)(d + 0) * NE_OUT + j];
        a1 += ul[d + 1] * wrec[(size_t)(d + 1) * NE_OUT + j];
        a2 += ul[d + 2] * wrec[(size_t)(d + 2) * NE_OUT + j];
        a3 += ul[d + 3] * wrec[(size_t)(d + 3) * NE_OUT + j];
    }
    out[j] = (a0 + a1) + (a2 + a3);
}

extern "C" void kernel_launch(void* const* d_in, const int* in_sizes, int n_in,
                              void* d_out, int out_size, void* d_ws, size_t ws_size,
                              hipStream_t stream)
{
    const float* ctx  = (const float*)d_in[9];
    const float* wq = (const float*)d_in[10];
    const float* bq = (const float*)d_in[11];
    const float* wk = (const float*)d_in[12];
    const float* bk = (const float*)d_in[13];
    const float* wv = (const float*)d_in[14];
    const float* bv = (const float*)d_in[15];
    const float* wo = (const float*)d_in[16];
    const float* bo = (const float*)d_in[17];
    const float* wrec = (const float*)d_in[18];
    const float* brec = (const float*)d_in[19];
    const int* node0 = (const int*)d_in[20];
    const int* edge0 = (const int*)d_in[21];
    const int* node1 = (const int*)d_in[22];
    const int* edge1 = (const int*)d_in[23];
    const int* node2 = (const int*)d_in[24];
    const int* edge2 = (const int*)d_in[25];
    float* out = (float*)d_out;

    char* ws = (char*)d_ws;
    size_t off = 0;
    auto alloc = [&](size_t nbytes) {
        void* p = ws + off;
        off += (nbytes + 255) & ~(size_t)255;
        return p;
    };
    unsigned short* rel  = (unsigned short*)alloc((size_t)R_REL * 128 * 2);
    unsigned short* xt   = (unsigned short*)alloc((size_t)3 * N_NODES * 128 * 2);
    unsigned short* eb   = (unsigned short*)alloc((size_t)3 * M_EDGES * 128 * 2);
    float* PRpart = (float*)alloc((size_t)4 * STRIPS * 128 * 128 * 4);   // 33.5 MB
    float* lpart  = (float*)alloc((size_t)4 * STRIPS * 128 * 4);
    unsigned short* qkb = (unsigned short*)alloc(512 * 128 * 2);
    float* cbv    = (float*)alloc(512 * 4);
    unsigned short* thT = (unsigned short*)alloc(3 * 16384 * 2);
    int* cntbase  = (int*)alloc((size_t)(3 * M_EDGES + 3 * N_NODES + 128) * 4); // + osum
    float* osum   = (float*)(cntbase + 3 * M_EDGES + 3 * N_NODES);
    int* offbase  = (int*)alloc((size_t)(3 * (M_EDGES + 1) + 3 * (N_NODES + 1)) * 4);
    int* listbase = (int*)alloc((size_t)6 * E_INC * 4);
    float* u      = (float*)alloc(128 * 4);
    (void)ws_size; (void)in_sizes; (void)n_in; (void)out_size;

    // 1. zero cnt + osum (contiguous)
    {
        int nwords = 3 * M_EDGES + 3 * N_NODES + 128;   // 210128, /4 = 52532
        zero_kernel<<<(nwords / 4 + 255) / 256, 256, 0, stream>>>((float4*)cntbase, nwords / 4);
    }
    // 2-4. CSR build
    const int gE = (E_INC + 255) / 256;
    count6_kernel<<<dim3(gE, 6), 256, 0, stream>>>(edge0, edge1, edge2, node0, node1, node2, cntbase);
    scan6_kernel<<<6, 1024, 0, stream>>>(cntbase, offbase);
    fill6_kernel<<<dim3(gE, 6), 256, 0, stream>>>(edge0, edge1, edge2, node0, node1, node2,
                                                  cntbase, offbase, listbase);
    // 5. weight conversion (theta^T bf16)
    wconv_kernel<<<192, 256, 0, stream>>>((const float*)d_in[1], (const float*)d_in[4],
                                          (const float*)d_in[7], thT);
    // 6. fused q projection + qk/cb precompute
    qkf_kernel<<<64, 256, 0, stream>>>(ctx, wq, bq, wk, bk, qkb, cbv);
    // 7. xt = x @ theta (bf16 MFMA), all modalities
    xg_kernel<<<dim3((N_NODES + 127) / 128, 3), 256, 0, stream>>>(
        (const float*)d_in[0], (const float*)d_in[3], (const float*)d_in[6], thT, xt, N_NODES);
    // 8-9. gathers (16 lanes per row, x4 unrolled degree loop)
    gedge_kernel<<<dim3(M_EDGES * 16 / 256, 3), 256, 0, stream>>>(xt, listbase, offbase, eb);
    gnode_kernel<<<dim3(N_NODES * 16 / 256, 3), 256, 0, stream>>>(
        eb, listbase, offbase, (const float*)d_in[2], (const float*)d_in[5],
        (const float*)d_in[8], rel);
    // 10-11. fused attention + reduce
    attn_kernel<<<dim3(STRIPS, 4), 256, 0, stream>>>(rel, qkb, cbv, PRpart, lpart);
    reduce_kernel<<<512, 256, 0, stream>>>(PRpart, lpart, wv, bv, osum);
    // 12-13. user repr + final scores
    user_kernel<<<1, 128, 0, stream>>>(ctx, osum, wo, bo, u);
    rec_kernel<<<(NE_OUT + 255) / 256, 256, 0, stream>>>(u, wrec, brec, out);
}